// Round 7
// baseline (365.955 us; speedup 1.0000x reference)
//
#include <hip/hip_runtime.h>
#include <cstdint>
#include <cstddef>

#define BB 8
#define NN 48
#define DD 33
#define XS 40            // xw/sw/ct row stride in floats (16B-aligned, zero-padded)
#define KP 128           // merged-K: [0,40)=xi*xj, [40,80)=xi*s, [80,120)=xj*s, 120=const
#define HH 32
#define MM (NN*NN)       // 2304 rows (i,j)
#define NC (NN*HH)       // 1536 cols (k,h)
#define TILE 96
#define TM (MM/TILE)     // 24 M-tiles
#define TN (NC/TILE)     // 16 N-tiles
#define NBLK (TM*TN)     // 384 gemm blocks per batch
#define NBLK_TOT (NBLK*BB) // 3072 gemm blocks total (ticket target)
#define ACHK (MM*16/256) // 144 A build blocks per batch
#define BCHK (NC*16/256) // 96  B build blocks per batch

typedef __attribute__((ext_vector_type(8))) _Float16 f16x8;
typedef __attribute__((ext_vector_type(4))) float f32x4;

// direct global->LDS DMA, 16B per lane; dest = wave-uniform base + lane*16
__device__ __forceinline__ void gload16(const void* g, void* l) {
    __builtin_amdgcn_global_load_lds(
        (const __attribute__((address_space(1))) unsigned int*)g,
        (__attribute__((address_space(3))) unsigned int*)l, 16, 0, 0);
}

// ---- Kernel A: gather xw (padded), s = mean_i x, transpose coefs -> ct,
// ----           precompute gk[b][k*32+h]; zero ticket counter ---------------------
__global__ void k_setup(const int* __restrict__ xcat, const float* __restrict__ xfeat,
                        const float* __restrict__ embed, const float* __restrict__ coefs,
                        const float* __restrict__ eq_bias,
                        float* __restrict__ xw, float* __restrict__ sw,
                        float* __restrict__ ct, float* __restrict__ gk,
                        unsigned int* __restrict__ counter) {
    int b = blockIdx.x, t = threadIdx.x;
    if (b < BB) {
        __shared__ float xl[NN * XS];        // batch feature rows (padded)
        __shared__ float sl[XS];
        __shared__ float c47[2][DD][HH];     // coefs columns q=4 (0) and q=7 (1)
        for (int idx = t; idx < 2 * DD * HH; idx += 256) {
            int q = idx / (DD * HH), r = idx - q * DD * HH;
            int d = r >> 5, h = r & 31;
            c47[q][d][h] = coefs[(d * 8 + (q ? 7 : 4)) * HH + h];
        }
        for (int idx = t; idx < NN * XS; idx += 256) {
            int i = idx / XS, d = idx - i * XS;
            float v = 0.f;
            if (d < 32)       v = embed[xcat[b * NN + i] * 32 + d];
            else if (d == 32) v = xfeat[b * NN + i];
            xl[idx] = v;
            xw[b * NN * XS + idx] = v;
        }
        __syncthreads();
        if (t < XS) {
            float a = 0.f;
            for (int i = 0; i < NN; ++i) a += xl[i * XS + t];
            float s = a * (1.0f / 48.0f);
            sw[b * XS + t] = s;
            sl[t] = s;
        }
        __syncthreads();
        // gk[b][k*32+h] = sum_d s^2 (c4[d,h]*x_k[d] + c7[d,h]*s[d]) + bias[h]
        for (int idx = t; idx < NC; idx += 256) {
            int k = idx >> 5, h = idx & 31;
            float g = 0.f;
            for (int d = 0; d < DD; ++d) {
                float sd = sl[d];
                g += sd * sd * (c47[0][d][h] * xl[k * XS + d] + c47[1][d][h] * sd);
            }
            gk[b * NC + idx] = g + eq_bias[h];
        }
    } else if (b == BB) {
        // ct[(q*32+h)*40 + d] = coefs[(d*8+q)*32 + h], zero-padded d>=33
        for (int idx = t; idx < 8 * HH * XS; idx += 256) {
            int qh = idx / XS, d = idx - qh * XS;
            int q = qh >> 5, h = qh & 31;
            ct[idx] = (d < DD) ? coefs[(d * 8 + q) * HH + h] : 0.f;
        }
    } else {
        if (t == 0) *counter = 0u;   // re-poison/replay safe
    }
}

// ---- Kernel B: build Aw[(b,i,j),128] and Bw[(b,k,h),128] f16, each row ONCE ------
// ---- XCD-affinity: linear block id & 7 == batch -> batch b stays on XCD b --------
__global__ __launch_bounds__(256) void k_build(
        const float* __restrict__ xw, const float* __restrict__ sw,
        const float* __restrict__ ct, const float* __restrict__ gk,
        _Float16* __restrict__ Aw, _Float16* __restrict__ Bw) {
    int t = threadIdx.x;
    int L = blockIdx.x;
    int b = L & 7;                  // XCD affinity: dispatch round-robins id%8
    int c = L >> 3;                 // [0, ACHK+BCHK)
    const float* xb = xw + b * NN * XS;
    const float* sb = sw + b * XS;
    if (c < ACHK) {
        int chunk = c * 256 + t;                  // chunk within batch A
        int row = chunk >> 4, d0 = (chunk & 15) * 8;   // row in [0,MM)
        int i = row / NN, j = row - i * NN;
        f16x8 v;
        if (d0 < 120) {
            int seg = (d0 >= 80) ? 2 : (d0 >= 40) ? 1 : 0;
            int d = d0 - seg * 40;
            const float* p1 = (seg == 2) ? (xb + j * XS) : (xb + i * XS);
            const float* p2 = (seg == 0) ? (xb + j * XS) : sb;
            f32x4 a0 = *(const f32x4*)(p1 + d), a1 = *(const f32x4*)(p1 + d + 4);
            f32x4 b0 = *(const f32x4*)(p2 + d), b1 = *(const f32x4*)(p2 + d + 4);
            f32x4 r0 = a0 * b0, r1 = a1 * b1;
            for (int e = 0; e < 4; ++e) { v[e] = (_Float16)r0[e]; v[4 + e] = (_Float16)r1[e]; }
        } else {
            v = (f16x8){0, 0, 0, 0, 0, 0, 0, 0};
            v[0] = (_Float16)1.f;
        }
        *(f16x8*)&Aw[((size_t)(b * MM + row)) * KP + d0] = v;
    } else {
        int chunk = (c - ACHK) * 256 + t;         // chunk within batch B
        int row = chunk >> 4, d0 = (chunk & 15) * 8;   // row in [0,NC)
        int k = row >> 5, h = row & 31;
        const float* xk = xb + k * XS;
        f16x8 v;
        if (d0 < 120) {
            int seg = (d0 >= 80) ? 2 : (d0 >= 40) ? 1 : 0;
            int d = d0 - seg * 40;
            const int QA[3] = {0, 2, 1}, QB[3] = {3, 6, 5};
            const float* ca = ct + (QA[seg] * HH + h) * XS + d;
            const float* cb = ct + (QB[seg] * HH + h) * XS + d;
            f32x4 ca0 = *(const f32x4*)(ca),     ca1 = *(const f32x4*)(ca + 4);
            f32x4 cb0 = *(const f32x4*)(cb),     cb1 = *(const f32x4*)(cb + 4);
            f32x4 xk0 = *(const f32x4*)(xk + d), xk1 = *(const f32x4*)(xk + d + 4);
            f32x4 sb0 = *(const f32x4*)(sb + d), sb1 = *(const f32x4*)(sb + d + 4);
            f32x4 r0 = ca0 * xk0 + cb0 * sb0;
            f32x4 r1 = ca1 * xk1 + cb1 * sb1;
            for (int e = 0; e < 4; ++e) { v[e] = (_Float16)r0[e]; v[4 + e] = (_Float16)r1[e]; }
        } else {
            v = (f16x8){0, 0, 0, 0, 0, 0, 0, 0};
            v[0] = (_Float16)gk[b * NC + row];
        }
        *(f16x8*)&Bw[((size_t)(b * NC + row)) * KP + d0] = v;
    }
}

// ---- Kernel C: pure 96x96x128 MFMA GEMM per block (3072 blocks, 1-D grid);
// ----           partial stores + ticket; LAST block reduces + writes out ----------
__global__ __launch_bounds__(256, 3) void k_gemm(
        const _Float16* __restrict__ Aw, const _Float16* __restrict__ Bw,
        float* __restrict__ partials, unsigned int* __restrict__ counter,
        const float* __restrict__ out_w, const float* __restrict__ out_b,
        float* __restrict__ out) {
    __shared__ __align__(16) _Float16 AsF[TILE * KP];   // linear [96][128], 24 KB
    __shared__ __align__(16) _Float16 BsF[TILE * KP];
    __shared__ float hacc[HH];
    __shared__ int lastFlag;

    int t = threadIdx.x;
    int lane = t & 63, wave = t >> 6;
    int L = blockIdx.x;
    int b = L & 7;                   // XCD affinity
    int tile = L >> 3;               // [0, 384)
    int bx = tile & 15, by = tile >> 4;
    int N0 = bx * TILE, M0 = by * TILE;
    const char* Agc = (const char*)(Aw + ((size_t)(b * MM + M0)) * KP);
    const char* Bgc = (const char*)(Bw + ((size_t)(b * NC + N0)) * KP);

    if (t < HH) hacc[t] = 0.f;

    // ---- stage both tiles: DMA 16B/lane; LDS linear, global source pre-swizzled ----
    // swizzle: data for LDS cell (row, c*16) comes from global byte (c*16)^((row&7)<<4)
#pragma unroll
    for (int c = 0; c < 6; ++c) {
        int row0 = c * 16 + wave * 4;            // wave-uniform base row (4 rows/wave)
        int row = row0 + (lane >> 4);
        int src = row * 256 + (((lane & 15) * 16) ^ ((row & 7) << 4));
        gload16(Agc + src, (char*)AsF + row0 * 256);
        gload16(Bgc + src, (char*)BsF + row0 * 256);
    }
    __syncthreads();   // compiler drains vmcnt(0) before barrier

    int lrow = lane & 15, quad = lane >> 4;

    f32x4 acc[3][3];
#pragma unroll
    for (int m3 = 0; m3 < 3; ++m3)
#pragma unroll
        for (int nt = 0; nt < 3; ++nt)
            acc[m3][nt] = (f32x4){0.f, 0.f, 0.f, 0.f};

    int wm = (wave >> 1) * 48, wn = (wave & 1) * 48;
#pragma unroll
    for (int ks = 0; ks < 4; ++ks) {
        int cb = ks * 64 + quad * 16;            // byte col of this lane's fragment
        f16x8 af[3], bf[3];
#pragma unroll
        for (int m3 = 0; m3 < 3; ++m3) {
            int R = wm + m3 * 16 + lrow;
            af[m3] = *(const f16x8*)((const char*)AsF + R * 256 + (cb ^ ((R & 7) << 4)));
        }
#pragma unroll
        for (int nt = 0; nt < 3; ++nt) {
            int R = wn + nt * 16 + lrow;
            bf[nt] = *(const f16x8*)((const char*)BsF + R * 256 + (cb ^ ((R & 7) << 4)));
        }
#pragma unroll
        for (int m3 = 0; m3 < 3; ++m3)
#pragma unroll
            for (int nt = 0; nt < 3; ++nt)
                acc[m3][nt] = __builtin_amdgcn_mfma_f32_16x16x32_f16(af[m3], bf[nt], acc[m3][nt], 0, 0, 0);
    }

    // ---- relu + reduce: quads -> LDS -> plain partial store ----
    float fs[3] = {0.f, 0.f, 0.f};
#pragma unroll
    for (int m3 = 0; m3 < 3; ++m3)
#pragma unroll
        for (int nt = 0; nt < 3; ++nt)
#pragma unroll
            for (int r = 0; r < 4; ++r)
                fs[nt] += fmaxf(acc[m3][nt][r], 0.f);

#pragma unroll
    for (int nt = 0; nt < 3; ++nt) {
        float v = fs[nt];
        v += __shfl_xor(v, 16);
        v += __shfl_xor(v, 32);
        if (lane < 16) atomicAdd(&hacc[(wn + nt * 16 + lane) & 31], v);
    }
    __syncthreads();
    if (t < HH) {
        int blockLin = by * TN + bx;
        partials[((size_t)b * NBLK + blockLin) * HH + t] = hacc[t];
    }
    // ---- ticket: one device atomic per block; last block finalizes ----
    __threadfence();               // make this block's partial store device-visible
    __syncthreads();
    if (t == 0) {
        unsigned int tk = atomicAdd(counter, 1u);
        lastFlag = (tk == NBLK_TOT - 1) ? 1 : 0;
    }
    __syncthreads();

    if (lastFlag) {
        __threadfence();           // acquire: invalidate caches before reading partials
        int lane2 = t & 63, w = t >> 6;        // 4 waves x 2 batches
#pragma unroll
        for (int e = 0; e < 2; ++e) {
            int bb = w * 2 + e;
            int h = lane2 & 31;
            float a = 0.f;
            for (int p = lane2 >> 5; p < NBLK; p += 2)
                a += partials[((size_t)bb * NBLK + p) * HH + h];
            a += __shfl_xor(a, 32);            // merge the two p-halves
            float r = fmaxf(a * (1.0f / 110592.0f), 0.f) * out_w[h];
            r += __shfl_xor(r, 1);
            r += __shfl_xor(r, 2);
            r += __shfl_xor(r, 4);
            r += __shfl_xor(r, 8);
            r += __shfl_xor(r, 16);
            if (lane2 == 0) out[bb] = r + out_b[0];
        }
    }
}

extern "C" void kernel_launch(void* const* d_in, const int* in_sizes, int n_in,
                              void* d_out, int out_size, void* d_ws, size_t ws_size,
                              hipStream_t stream) {
    (void)in_sizes; (void)n_in; (void)out_size; (void)ws_size;
    const int*   xcat    = (const int*)d_in[0];
    const float* xfeat   = (const float*)d_in[1];
    const float* embed   = (const float*)d_in[2];
    const float* coefs   = (const float*)d_in[3];
    const float* eq_bias = (const float*)d_in[4];
    const float* out_w   = (const float*)d_in[5];
    const float* out_b   = (const float*)d_in[6];
    float* out = (float*)d_out;

    // Workspace layout (16B-aligned), total ~8.4 MB
    char* w = (char*)d_ws;
    float*        xw       = (float*)(w + 0);        // 8*48*40 f32   = 61440 B
    float*        sw       = (float*)(w + 61440);    // 8*40 f32      = 1280 B
    float*        ct       = (float*)(w + 62720);    // 8*32*40 f32   = 40960 B
    float*        gk       = (float*)(w + 103680);   // 8*1536 f32    = 49152 B
    _Float16*     Aw       = (_Float16*)(w + 152832);// 8*2304*128 f16 = 4718592 B
    _Float16*     Bw       = (_Float16*)(w + 4871424);// 8*1536*128 f16 = 3145728 B
    float*        partials = (float*)(w + 8017152);  // 8*384*32 f32  = 393216 B
    unsigned int* counter  = (unsigned int*)(w + 8410368); // 4 B

    k_setup<<<dim3(BB + 2), dim3(256), 0, stream>>>(xcat, xfeat, embed, coefs, eq_bias,
                                                    xw, sw, ct, gk, counter);
    k_build<<<dim3((ACHK + BCHK) * BB), dim3(256), 0, stream>>>(xw, sw, ct, gk, Aw, Bw);
    k_gemm<<<dim3(TM * TN * BB), dim3(256), 0, stream>>>(Aw, Bw, partials, counter,
                                                         out_w, out_b, out);
}

// Round 8
// 108.536 us; speedup vs baseline: 3.3717x; 3.3717x over previous
//
#include <hip/hip_runtime.h>
#include <cstdint>
#include <cstddef>

#define BB 8
#define NN 48
#define DD 33
#define XS 40            // xw/sw/ct row stride in floats (16B-aligned, zero-padded)
#define KP 128           // merged-K: [0,40)=xi*xj, [40,80)=xi*s, [80,120)=xj*s, 120=const
#define HH 32
#define MM (NN*NN)       // 2304 rows (i,j)
#define NC (NN*HH)       // 1536 cols (k,h)
#define TILE 96
#define TM (MM/TILE)     // 24 M-tiles
#define TN (NC/TILE)     // 16 N-tiles
#define NBLK (TM*TN)     // 384 blocks per batch
#define ACHK (MM*16/256) // 144 A build blocks per batch
#define BCHK (NC*16/256) // 96  B build blocks per batch

typedef __attribute__((ext_vector_type(8))) _Float16 f16x8;
typedef __attribute__((ext_vector_type(4))) float f32x4;

// direct global->LDS DMA, 16B per lane; dest = wave-uniform base + lane*16
__device__ __forceinline__ void gload16(const void* g, void* l) {
    __builtin_amdgcn_global_load_lds(
        (const __attribute__((address_space(1))) unsigned int*)g,
        (__attribute__((address_space(3))) unsigned int*)l, 16, 0, 0);
}

// ---- Kernel A: gather xw (padded), s = mean_i x, transpose coefs -> ct,
// ----           precompute const-column gk[b][k*32+h] (all from LDS) --------------
__global__ void k_setup(const int* __restrict__ xcat, const float* __restrict__ xfeat,
                        const float* __restrict__ embed, const float* __restrict__ coefs,
                        const float* __restrict__ eq_bias,
                        float* __restrict__ xw, float* __restrict__ sw,
                        float* __restrict__ ct, float* __restrict__ gk) {
    int b = blockIdx.x, t = threadIdx.x;
    if (b < BB) {
        __shared__ float xl[NN * XS];        // batch feature rows (padded)
        __shared__ float sl[XS];
        __shared__ float c47[2][DD][HH];     // coefs columns q=4 (0) and q=7 (1)
        for (int idx = t; idx < 2 * DD * HH; idx += 256) {
            int q = idx / (DD * HH), r = idx - q * DD * HH;
            int d = r >> 5, h = r & 31;
            c47[q][d][h] = coefs[(d * 8 + (q ? 7 : 4)) * HH + h];
        }
        for (int idx = t; idx < NN * XS; idx += 256) {
            int i = idx / XS, d = idx - i * XS;
            float v = 0.f;
            if (d < 32)       v = embed[xcat[b * NN + i] * 32 + d];
            else if (d == 32) v = xfeat[b * NN + i];
            xl[idx] = v;
            xw[b * NN * XS + idx] = v;
        }
        __syncthreads();
        if (t < XS) {
            float a = 0.f;
            for (int i = 0; i < NN; ++i) a += xl[i * XS + t];
            float s = a * (1.0f / 48.0f);
            sw[b * XS + t] = s;
            sl[t] = s;
        }
        __syncthreads();
        // gk[b][k*32+h] = sum_d s^2 (c4[d,h]*x_k[d] + c7[d,h]*s[d]) + bias[h]
        for (int idx = t; idx < NC; idx += 256) {
            int k = idx >> 5, h = idx & 31;
            float g = 0.f;
            for (int d = 0; d < DD; ++d) {
                float sd = sl[d];
                g += sd * sd * (c47[0][d][h] * xl[k * XS + d] + c47[1][d][h] * sd);
            }
            gk[b * NC + idx] = g + eq_bias[h];
        }
    } else {
        // ct[(q*32+h)*40 + d] = coefs[(d*8+q)*32 + h], zero-padded d>=33
        for (int idx = t; idx < 8 * HH * XS; idx += 256) {
            int qh = idx / XS, d = idx - qh * XS;
            int q = qh >> 5, h = qh & 31;
            ct[idx] = (d < DD) ? coefs[(d * 8 + q) * HH + h] : 0.f;
        }
    }
}

// ---- Kernel B: build Aw[(b,i,j),128] and Bw[(b,k,h),128] f16, each row ONCE ------
// ---- XCD-affinity: linear block id & 7 == batch -> batch b stays on XCD b --------
__global__ __launch_bounds__(256) void k_build(
        const float* __restrict__ xw, const float* __restrict__ sw,
        const float* __restrict__ ct, const float* __restrict__ gk,
        _Float16* __restrict__ Aw, _Float16* __restrict__ Bw) {
    int t = threadIdx.x;
    int L = blockIdx.x;
    int b = L & 7;                  // XCD affinity: dispatch round-robins id%8
    int c = L >> 3;                 // [0, ACHK+BCHK)
    const float* xb = xw + b * NN * XS;
    const float* sb = sw + b * XS;
    if (c < ACHK) {
        int chunk = c * 256 + t;                  // chunk within batch A
        int row = chunk >> 4, d0 = (chunk & 15) * 8;   // row in [0,MM)
        int i = row / NN, j = row - i * NN;
        f16x8 v;
        if (d0 < 120) {
            int seg = (d0 >= 80) ? 2 : (d0 >= 40) ? 1 : 0;
            int d = d0 - seg * 40;
            const float* p1 = (seg == 2) ? (xb + j * XS) : (xb + i * XS);
            const float* p2 = (seg == 0) ? (xb + j * XS) : sb;
            f32x4 a0 = *(const f32x4*)(p1 + d), a1 = *(const f32x4*)(p1 + d + 4);
            f32x4 b0 = *(const f32x4*)(p2 + d), b1 = *(const f32x4*)(p2 + d + 4);
            f32x4 r0 = a0 * b0, r1 = a1 * b1;
            for (int e = 0; e < 4; ++e) { v[e] = (_Float16)r0[e]; v[4 + e] = (_Float16)r1[e]; }
        } else {
            v = (f16x8){0, 0, 0, 0, 0, 0, 0, 0};
            v[0] = (_Float16)1.f;
        }
        *(f16x8*)&Aw[((size_t)(b * MM + row)) * KP + d0] = v;
    } else {
        int chunk = (c - ACHK) * 256 + t;         // chunk within batch B
        int row = chunk >> 4, d0 = (chunk & 15) * 8;   // row in [0,NC)
        int k = row >> 5, h = row & 31;
        const float* xk = xb + k * XS;
        f16x8 v;
        if (d0 < 120) {
            int seg = (d0 >= 80) ? 2 : (d0 >= 40) ? 1 : 0;
            int d = d0 - seg * 40;
            const int QA[3] = {0, 2, 1}, QB[3] = {3, 6, 5};
            const float* ca = ct + (QA[seg] * HH + h) * XS + d;
            const float* cb = ct + (QB[seg] * HH + h) * XS + d;
            f32x4 ca0 = *(const f32x4*)(ca),     ca1 = *(const f32x4*)(ca + 4);
            f32x4 cb0 = *(const f32x4*)(cb),     cb1 = *(const f32x4*)(cb + 4);
            f32x4 xk0 = *(const f32x4*)(xk + d), xk1 = *(const f32x4*)(xk + d + 4);
            f32x4 sb0 = *(const f32x4*)(sb + d), sb1 = *(const f32x4*)(sb + d + 4);
            f32x4 r0 = ca0 * xk0 + cb0 * sb0;
            f32x4 r1 = ca1 * xk1 + cb1 * sb1;
            for (int e = 0; e < 4; ++e) { v[e] = (_Float16)r0[e]; v[4 + e] = (_Float16)r1[e]; }
        } else {
            v = (f16x8){0, 0, 0, 0, 0, 0, 0, 0};
            v[0] = (_Float16)gk[b * NC + row];
        }
        *(f16x8*)&Bw[((size_t)(b * NC + row)) * KP + d0] = v;
    }
}

// ---- Kernel C: pure 96x96x128 MFMA GEMM per block (3072 blocks, 1-D grid);
// ----           XCD-affinity swizzle: id&7 = batch -> tile reuse hits own-XCD L2 --
__global__ __launch_bounds__(256, 3) void k_gemm(
        const _Float16* __restrict__ Aw, const _Float16* __restrict__ Bw,
        float* __restrict__ partials) {
    __shared__ __align__(16) _Float16 AsF[TILE * KP];   // linear [96][128], 24 KB
    __shared__ __align__(16) _Float16 BsF[TILE * KP];
    __shared__ float hacc[HH];

    int t = threadIdx.x;
    int lane = t & 63, wave = t >> 6;
    int L = blockIdx.x;
    int b = L & 7;                   // XCD affinity
    int tile = L >> 3;               // [0, 384)
    int bx = tile & 15, by = tile >> 4;
    int N0 = bx * TILE, M0 = by * TILE;
    const char* Agc = (const char*)(Aw + ((size_t)(b * MM + M0)) * KP);
    const char* Bgc = (const char*)(Bw + ((size_t)(b * NC + N0)) * KP);

    if (t < HH) hacc[t] = 0.f;

    // ---- stage both tiles: DMA 16B/lane; LDS linear, global source pre-swizzled ----
    // swizzle: data for LDS cell (row, c*16) comes from global byte (c*16)^((row&7)<<4)
#pragma unroll
    for (int c = 0; c < 6; ++c) {
        int row0 = c * 16 + wave * 4;            // wave-uniform base row (4 rows/wave)
        int row = row0 + (lane >> 4);
        int src = row * 256 + (((lane & 15) * 16) ^ ((row & 7) << 4));
        gload16(Agc + src, (char*)AsF + row0 * 256);
        gload16(Bgc + src, (char*)BsF + row0 * 256);
    }
    __syncthreads();   // compiler drains vmcnt(0) before barrier

    int lrow = lane & 15, quad = lane >> 4;

    f32x4 acc[3][3];
#pragma unroll
    for (int m3 = 0; m3 < 3; ++m3)
#pragma unroll
        for (int nt = 0; nt < 3; ++nt)
            acc[m3][nt] = (f32x4){0.f, 0.f, 0.f, 0.f};

    int wm = (wave >> 1) * 48, wn = (wave & 1) * 48;
#pragma unroll
    for (int ks = 0; ks < 4; ++ks) {
        int cb = ks * 64 + quad * 16;            // byte col of this lane's fragment
        f16x8 af[3], bf[3];
#pragma unroll
        for (int m3 = 0; m3 < 3; ++m3) {
            int R = wm + m3 * 16 + lrow;
            af[m3] = *(const f16x8*)((const char*)AsF + R * 256 + (cb ^ ((R & 7) << 4)));
        }
#pragma unroll
        for (int nt = 0; nt < 3; ++nt) {
            int R = wn + nt * 16 + lrow;
            bf[nt] = *(const f16x8*)((const char*)BsF + R * 256 + (cb ^ ((R & 7) << 4)));
        }
#pragma unroll
        for (int m3 = 0; m3 < 3; ++m3)
#pragma unroll
            for (int nt = 0; nt < 3; ++nt)
                acc[m3][nt] = __builtin_amdgcn_mfma_f32_16x16x32_f16(af[m3], bf[nt], acc[m3][nt], 0, 0, 0);
    }

    // ---- relu + reduce: quads -> LDS -> plain partial store ----
    float fs[3] = {0.f, 0.f, 0.f};
#pragma unroll
    for (int m3 = 0; m3 < 3; ++m3)
#pragma unroll
        for (int nt = 0; nt < 3; ++nt)
#pragma unroll
            for (int r = 0; r < 4; ++r)
                fs[nt] += fmaxf(acc[m3][nt][r], 0.f);

#pragma unroll
    for (int nt = 0; nt < 3; ++nt) {
        float v = fs[nt];
        v += __shfl_xor(v, 16);
        v += __shfl_xor(v, 32);
        if (lane < 16) atomicAdd(&hacc[(wn + nt * 16 + lane) & 31], v);
    }
    __syncthreads();
    if (t < HH) {
        int blockLin = by * TN + bx;
        partials[((size_t)b * NBLK + blockLin) * HH + t] = hacc[t];
    }
}

// ---- Kernel D: per-batch reduce -> relu(mean) @ out_w + out_b ---------------------
__global__ void k_final(const float* __restrict__ partials, const float* __restrict__ out_w,
                        const float* __restrict__ out_b, float* __restrict__ out) {
    __shared__ float red[256];
    int b = blockIdx.x, t = threadIdx.x;
    int h = t & 31, g = t >> 5;
    float a = 0.f;
    for (int p = g; p < NBLK; p += 8) a += partials[((size_t)b * NBLK + p) * HH + h];
    red[t] = a;
    __syncthreads();
    if (t < HH) {
        float tot = 0.f;
        for (int gg = 0; gg < 8; ++gg) tot += red[gg * 32 + t];
        float m = tot * (1.0f / 110592.0f);
        red[t] = fmaxf(m, 0.f) * out_w[t];
    }
    __syncthreads();
    if (t == 0) {
        float o = 0.f;
        for (int h2 = 0; h2 < HH; ++h2) o += red[h2];
        out[b] = o + out_b[0];
    }
}

extern "C" void kernel_launch(void* const* d_in, const int* in_sizes, int n_in,
                              void* d_out, int out_size, void* d_ws, size_t ws_size,
                              hipStream_t stream) {
    (void)in_sizes; (void)n_in; (void)out_size; (void)ws_size;
    const int*   xcat    = (const int*)d_in[0];
    const float* xfeat   = (const float*)d_in[1];
    const float* embed   = (const float*)d_in[2];
    const float* coefs   = (const float*)d_in[3];
    const float* eq_bias = (const float*)d_in[4];
    const float* out_w   = (const float*)d_in[5];
    const float* out_b   = (const float*)d_in[6];
    float* out = (float*)d_out;

    // Workspace layout (16B-aligned), total ~8.4 MB
    char* w = (char*)d_ws;
    float*    xw       = (float*)(w + 0);        // 8*48*40 f32   = 61440 B
    float*    sw       = (float*)(w + 61440);    // 8*40 f32      = 1280 B
    float*    ct       = (float*)(w + 62720);    // 8*32*40 f32   = 40960 B
    float*    gk       = (float*)(w + 103680);   // 8*1536 f32    = 49152 B
    _Float16* Aw       = (_Float16*)(w + 152832);// 8*2304*128 f16 = 4718592 B
    _Float16* Bw       = (_Float16*)(w + 4871424);// 8*1536*128 f16 = 3145728 B
    float*    partials = (float*)(w + 8017152);  // 8*384*32 f32  = 393216 B

    k_setup<<<dim3(BB + 1), dim3(256), 0, stream>>>(xcat, xfeat, embed, coefs, eq_bias,
                                                    xw, sw, ct, gk);
    k_build<<<dim3((ACHK + BCHK) * BB), dim3(256), 0, stream>>>(xw, sw, ct, gk, Aw, Bw);
    k_gemm<<<dim3(TM * TN * BB), dim3(256), 0, stream>>>(Aw, Bw, partials);
    k_final<<<dim3(BB), dim3(256), 0, stream>>>(partials, out_w, out_b, out);
}

// Round 9
// 106.728 us; speedup vs baseline: 3.4288x; 1.0169x over previous
//
#include <hip/hip_runtime.h>
#include <cstdint>
#include <cstddef>

#define BB 8
#define NN 48
#define DD 33
#define XS 40            // xl/sl row stride in floats (16B-aligned, zero-padded)
#define KP 128           // merged-K: [0,40)=xi*xj, [40,80)=xi*s, [80,120)=xj*s, 120=const
#define HH 32
#define MM (NN*NN)       // 2304 rows (i,j)
#define NC (NN*HH)       // 1536 cols (k,h)
#define TILE 96
#define TM (MM/TILE)     // 24 M-tiles
#define TN (NC/TILE)     // 16 N-tiles
#define NBLK (TM*TN)     // 384 gemm blocks per batch
#define ACHK (MM*16/256) // 144 A build blocks per batch
#define BCHK (NC*16/256) // 96  B build blocks per batch

typedef __attribute__((ext_vector_type(8))) _Float16 f16x8;
typedef __attribute__((ext_vector_type(4))) float f32x4;

// direct global->LDS DMA, 16B per lane; dest = wave-uniform base + lane*16
__device__ __forceinline__ void gload16(const void* g, void* l) {
    __builtin_amdgcn_global_load_lds(
        (const __attribute__((address_space(1))) unsigned int*)g,
        (__attribute__((address_space(3))) unsigned int*)l, 16, 0, 0);
}

// ---- Kernel A (fused setup+build): each block gathers its batch's features into
// ---- LDS, computes the mean row, and builds its A/B chunks from raw inputs.
// ---- XCD-affinity: linear block id & 7 == batch -> batch b stays on XCD b --------
__global__ __launch_bounds__(256) void k_build(
        const int* __restrict__ xcat, const float* __restrict__ xfeat,
        const float* __restrict__ embed, const float* __restrict__ coefs,
        const float* __restrict__ eq_bias,
        _Float16* __restrict__ Aw, _Float16* __restrict__ Bw) {
    __shared__ float xl[NN * XS];        // batch feature rows, pad cols zeroed
    __shared__ float sl[XS];             // column means (pad cols zero)
    int t = threadIdx.x;
    int L = blockIdx.x;
    int b = L & 7;                       // XCD affinity: dispatch round-robins id%8
    int c = L >> 3;                      // [0, ACHK+BCHK)

    // gather embed rows + xfeat into LDS (L2-resident table; ~1.9K dwords/block)
    for (int idx = t; idx < NN * XS; idx += 256) {
        int i = idx / XS, d = idx - i * XS;
        float v = 0.f;
        if (d < 32)       v = embed[xcat[b * NN + i] * 32 + d];
        else if (d == 32) v = xfeat[b * NN + i];
        xl[idx] = v;
    }
    __syncthreads();
    if (t < XS) {
        float a = 0.f;
        for (int i = 0; i < NN; ++i) a += xl[i * XS + t];
        sl[t] = a * (1.0f / 48.0f);
    }
    __syncthreads();

    if (c < ACHK) {
        // ---- A chunk: row (i,j), 8 cols starting at d0 ----
        int chunk = c * 256 + t;
        int row = chunk >> 4, d0 = (chunk & 15) * 8;   // row in [0,MM)
        int i = row / NN, j = row - i * NN;
        f16x8 v;
        if (d0 < 120) {
            int seg = (d0 >= 80) ? 2 : (d0 >= 40) ? 1 : 0;
            int d = d0 - seg * 40;
            const float* p1 = (seg == 2) ? (xl + j * XS) : (xl + i * XS);
            const float* p2 = (seg == 0) ? (xl + j * XS) : sl;
            f32x4 a0 = *(const f32x4*)(p1 + d), a1 = *(const f32x4*)(p1 + d + 4);
            f32x4 b0 = *(const f32x4*)(p2 + d), b1 = *(const f32x4*)(p2 + d + 4);
            f32x4 r0 = a0 * b0, r1 = a1 * b1;
            for (int e = 0; e < 4; ++e) { v[e] = (_Float16)r0[e]; v[4 + e] = (_Float16)r1[e]; }
        } else {
            v = (f16x8){0, 0, 0, 0, 0, 0, 0, 0};
            v[0] = (_Float16)1.f;
        }
        *(f16x8*)&Aw[((size_t)(b * MM + row)) * KP + d0] = v;
    } else {
        // ---- B chunk: row (k,h), 8 cols starting at d0; coefs read directly ----
        int chunk = (c - ACHK) * 256 + t;
        int row = chunk >> 4, d0 = (chunk & 15) * 8;   // row in [0,NC)
        int k = row >> 5, h = row & 31;
        f16x8 v;
        if (d0 < 120) {
            int seg = (d0 >= 80) ? 2 : (d0 >= 40) ? 1 : 0;
            int d = d0 - seg * 40;
            const int QA[3] = {0, 2, 1}, QB[3] = {3, 6, 5};
            int qa = QA[seg], qb = QB[seg];
#pragma unroll
            for (int e = 0; e < 8; ++e) {
                int dd = d + e;
                float ca = (dd < DD) ? coefs[(dd * 8 + qa) * HH + h] : 0.f;
                float cb = (dd < DD) ? coefs[(dd * 8 + qb) * HH + h] : 0.f;
                v[e] = (_Float16)(ca * xl[k * XS + dd] + cb * sl[dd]);
            }
        } else {
            // const-K column: g = sum_d s^2 (c4*x_k + c7*s) + bias_h
            float g = 0.f;
            for (int d = 0; d < DD; ++d) {
                float sd = sl[d];
                g += sd * sd * (coefs[(d * 8 + 4) * HH + h] * xl[k * XS + d]
                              + coefs[(d * 8 + 7) * HH + h] * sd);
            }
            v = (f16x8){0, 0, 0, 0, 0, 0, 0, 0};
            v[0] = (_Float16)(g + eq_bias[h]);
        }
        *(f16x8*)&Bw[((size_t)(b * NC + row)) * KP + d0] = v;
    }
}

// ---- Kernel B: pure 96x96x128 MFMA GEMM per block (3072 blocks, 1-D grid);
// ----           XCD-affinity swizzle: id&7 = batch -> tile reuse hits own-XCD L2 --
__global__ __launch_bounds__(256, 3) void k_gemm(
        const _Float16* __restrict__ Aw, const _Float16* __restrict__ Bw,
        float* __restrict__ partials) {
    __shared__ __align__(16) _Float16 AsF[TILE * KP];   // linear [96][128], 24 KB
    __shared__ __align__(16) _Float16 BsF[TILE * KP];
    __shared__ float hacc[HH];

    int t = threadIdx.x;
    int lane = t & 63, wave = t >> 6;
    int L = blockIdx.x;
    int b = L & 7;                   // XCD affinity
    int tile = L >> 3;               // [0, 384)
    int bx = tile & 15, by = tile >> 4;
    int N0 = bx * TILE, M0 = by * TILE;
    const char* Agc = (const char*)(Aw + ((size_t)(b * MM + M0)) * KP);
    const char* Bgc = (const char*)(Bw + ((size_t)(b * NC + N0)) * KP);

    if (t < HH) hacc[t] = 0.f;

    // ---- stage both tiles: DMA 16B/lane; LDS linear, global source pre-swizzled ----
    // swizzle: data for LDS cell (row, c*16) comes from global byte (c*16)^((row&7)<<4)
#pragma unroll
    for (int c = 0; c < 6; ++c) {
        int row0 = c * 16 + wave * 4;            // wave-uniform base row (4 rows/wave)
        int row = row0 + (lane >> 4);
        int src = row * 256 + (((lane & 15) * 16) ^ ((row & 7) << 4));
        gload16(Agc + src, (char*)AsF + row0 * 256);
        gload16(Bgc + src, (char*)BsF + row0 * 256);
    }
    __syncthreads();   // compiler drains vmcnt(0) before barrier

    int lrow = lane & 15, quad = lane >> 4;

    f32x4 acc[3][3];
#pragma unroll
    for (int m3 = 0; m3 < 3; ++m3)
#pragma unroll
        for (int nt = 0; nt < 3; ++nt)
            acc[m3][nt] = (f32x4){0.f, 0.f, 0.f, 0.f};

    int wm = (wave >> 1) * 48, wn = (wave & 1) * 48;
#pragma unroll
    for (int ks = 0; ks < 4; ++ks) {
        int cb = ks * 64 + quad * 16;            // byte col of this lane's fragment
        f16x8 af[3], bf[3];
#pragma unroll
        for (int m3 = 0; m3 < 3; ++m3) {
            int R = wm + m3 * 16 + lrow;
            af[m3] = *(const f16x8*)((const char*)AsF + R * 256 + (cb ^ ((R & 7) << 4)));
        }
#pragma unroll
        for (int nt = 0; nt < 3; ++nt) {
            int R = wn + nt * 16 + lrow;
            bf[nt] = *(const f16x8*)((const char*)BsF + R * 256 + (cb ^ ((R & 7) << 4)));
        }
#pragma unroll
        for (int m3 = 0; m3 < 3; ++m3)
#pragma unroll
            for (int nt = 0; nt < 3; ++nt)
                acc[m3][nt] = __builtin_amdgcn_mfma_f32_16x16x32_f16(af[m3], bf[nt], acc[m3][nt], 0, 0, 0);
    }

    // ---- relu + reduce: quads -> LDS -> plain partial store ----
    float fs[3] = {0.f, 0.f, 0.f};
#pragma unroll
    for (int m3 = 0; m3 < 3; ++m3)
#pragma unroll
        for (int nt = 0; nt < 3; ++nt)
#pragma unroll
            for (int r = 0; r < 4; ++r)
                fs[nt] += fmaxf(acc[m3][nt][r], 0.f);

#pragma unroll
    for (int nt = 0; nt < 3; ++nt) {
        float v = fs[nt];
        v += __shfl_xor(v, 16);
        v += __shfl_xor(v, 32);
        if (lane < 16) atomicAdd(&hacc[(wn + nt * 16 + lane) & 31], v);
    }
    __syncthreads();
    if (t < HH) {
        int blockLin = by * TN + bx;
        partials[((size_t)b * NBLK + blockLin) * HH + t] = hacc[t];
    }
}

// ---- Kernel C: per-batch reduce -> relu(mean) @ out_w + out_b ---------------------
__global__ void k_final(const float* __restrict__ partials, const float* __restrict__ out_w,
                        const float* __restrict__ out_b, float* __restrict__ out) {
    __shared__ float red[256];
    int b = blockIdx.x, t = threadIdx.x;
    int h = t & 31, g = t >> 5;
    float a = 0.f;
    for (int p = g; p < NBLK; p += 8) a += partials[((size_t)b * NBLK + p) * HH + h];
    red[t] = a;
    __syncthreads();
    if (t < HH) {
        float tot = 0.f;
        for (int gg = 0; gg < 8; ++gg) tot += red[gg * 32 + t];
        float m = tot * (1.0f / 110592.0f);
        red[t] = fmaxf(m, 0.f) * out_w[t];
    }
    __syncthreads();
    if (t == 0) {
        float o = 0.f;
        for (int h2 = 0; h2 < HH; ++h2) o += red[h2];
        out[b] = o + out_b[0];
    }
}

extern "C" void kernel_launch(void* const* d_in, const int* in_sizes, int n_in,
                              void* d_out, int out_size, void* d_ws, size_t ws_size,
                              hipStream_t stream) {
    (void)in_sizes; (void)n_in; (void)out_size; (void)ws_size;
    const int*   xcat    = (const int*)d_in[0];
    const float* xfeat   = (const float*)d_in[1];
    const float* embed   = (const float*)d_in[2];
    const float* coefs   = (const float*)d_in[3];
    const float* eq_bias = (const float*)d_in[4];
    const float* out_w   = (const float*)d_in[5];
    const float* out_b   = (const float*)d_in[6];
    float* out = (float*)d_out;

    // Workspace layout (16B-aligned), total ~8.26 MB
    char* w = (char*)d_ws;
    _Float16* Aw       = (_Float16*)(w + 0);       // 8*2304*128 f16 = 4718592 B
    _Float16* Bw       = (_Float16*)(w + 4718592); // 8*1536*128 f16 = 3145728 B
    float*    partials = (float*)(w + 7864320);    // 8*384*32 f32   = 393216 B

    k_build<<<dim3((ACHK + BCHK) * BB), dim3(256), 0, stream>>>(xcat, xfeat, embed, coefs,
                                                                eq_bias, Aw, Bw);
    k_gemm<<<dim3(TM * TN * BB), dim3(256), 0, stream>>>(Aw, Bw, partials);
    k_final<<<dim3(BB), dim3(256), 0, stream>>>(partials, out_w, out_b, out);
}